// Round 15
// baseline (238.886 us; speedup 1.0000x reference)
//
#include <hip/hip_runtime.h>

// Problem constants
#define B_   2
#define S_   2048
#define H_   2048
#define NH_  16
#define G_   4
#define HD_  128
#define KV_  512
#define HQKV 3072   // fused Q|K|V output width

typedef __attribute__((ext_vector_type(8))) short bf16x8;
typedef __attribute__((ext_vector_type(4))) float f32x4;

__device__ __forceinline__ unsigned short f2bf(float f) {
    unsigned u = __float_as_uint(f);
    u += 0x7fff + ((u >> 16) & 1);   // RNE
    return (unsigned short)(u >> 16);
}
__device__ __forceinline__ float bf2f(unsigned short s) {
    return __uint_as_float(((unsigned)s) << 16);
}
// D.lo = bf16(a), D.hi = bf16(b)  (RNE)
__device__ __forceinline__ unsigned cvtpk(float a, float b) {
    unsigned r;
    asm volatile("v_cvt_pk_bf16_f32 %0, %1, %2" : "=v"(r) : "v"(a), "v"(b));
    return r;
}

#define GLDS16(gsrc, ldst)                                                            \
    __builtin_amdgcn_global_load_lds(                                                 \
        (const __attribute__((address_space(1))) void*)(gsrc),                        \
        (__attribute__((address_space(3))) void*)(ldst), 16, 0, 0)

// 1/sqrt(128) * log2(e): folded into Q columns of the QKV GEMM epilogue
#define SC2F (0.08838834764831843f * 1.4426950408889634f)

// ---------------- fused prep: cvt X | transpose Wq/Wk/Wv | transpose Wo | bias ----------------
// Block ranges: [0,8192) cvt X float4 (2,097,152 float4s = ALL of X, both batches);
// [8192,14336) Wqkv transpose (96x64); [14336,18432) Wo transpose (64x64);
// [18432,18444) bias concat.
__global__ __launch_bounds__(256) void k_prep(
    const float* __restrict__ X,  const float* __restrict__ Wq,
    const float* __restrict__ Wk, const float* __restrict__ Wv,
    const float* __restrict__ Wo, const float* __restrict__ bq,
    const float* __restrict__ bk, const float* __restrict__ bv,
    unsigned short* __restrict__ Xb, unsigned short* __restrict__ WqkvT,
    unsigned short* __restrict__ WoT, float* __restrict__ bqkv) {
    __shared__ float t[32][33];
    const int bid = blockIdx.x, tid = threadIdx.x;
    if (bid < 8192) {                       // X fp32 -> bf16 (2,097,152 float4s)
        int i = bid * 256 + tid;
        float4 v = ((const float4*)X)[i];
        ushort4 o;
        o.x = f2bf(v.x); o.y = f2bf(v.y); o.z = f2bf(v.z); o.w = f2bf(v.w);
        ((ushort4*)Xb)[i] = o;
        return;
    }
    const int tx = tid & 31, ty = tid >> 5;  // 32 x 8
    if (bid < 14336) {                      // Wq|Wk|Wv -> WqkvT [3072][2048]
        int idx = bid - 8192;
        int n0g = (idx % 96) * 32, h0 = (idx / 96) * 32;
        const float* src; int C, n0l;
        if (n0g < H_)            { src = Wq; C = H_;  n0l = n0g; }
        else if (n0g < H_ + KV_) { src = Wk; C = KV_; n0l = n0g - H_; }
        else                     { src = Wv; C = KV_; n0l = n0g - H_ - KV_; }
#pragma unroll
        for (int i = 0; i < 4; ++i)
            t[ty + i*8][tx] = src[(size_t)(h0 + ty + i*8) * C + n0l + tx];
        __syncthreads();
#pragma unroll
        for (int i = 0; i < 4; ++i)
            WqkvT[(size_t)(n0g + ty + i*8) * H_ + h0 + tx] = f2bf(t[tx][ty + i*8]);
        return;
    }
    if (bid < 18432) {                      // Wo -> WoT [2048][2048]
        int idx = bid - 14336;
        int c0 = (idx % 64) * 32, r0 = (idx / 64) * 32;
#pragma unroll
        for (int i = 0; i < 4; ++i)
            t[ty + i*8][tx] = Wo[(size_t)(r0 + ty + i*8) * H_ + c0 + tx];
        __syncthreads();
#pragma unroll
        for (int i = 0; i < 4; ++i)
            WoT[(size_t)(c0 + ty + i*8) * H_ + r0 + tx] = f2bf(t[tx][ty + i*8]);
        return;
    }
    int i = (bid - 18432) * 256 + tid;      // bias concat [3072]
    if (i < HQKV)
        bqkv[i] = (i < H_) ? bq[i] : (i < H_ + KV_ ? bk[i - H_] : bv[i - H_ - KV_]);
}

// ---------------- 256x128 8-phase bf16 GEMM (validated R11/R14 engine) ----------------
// 8 waves (2x4), per-wave C = 128x32, acc[8][2]. B-stripes at bit4 granularity.
// Ledger: prologue 9 in flight; tile-top vmcnt(3); last tile vmcnt(0). LDS 96 KB.
// QVT (QKV mode): cols < H_ scaled by SC2F; cols >= H_+KV_ (V) written ONLY to
// VbT[b][vcol][s] (transposed). V-blocks are the last blockIdx.y values -> they
// run in the half-idle second round of a 384-block grid.
template <bool BF16OUT, bool QVT>
__global__ __launch_bounds__(512, 1) void k_gemm256x128(
    const unsigned short* __restrict__ A, const unsigned short* __restrict__ Bt,
    const float* __restrict__ bias, void* __restrict__ Cout,
    unsigned short* __restrict__ VbT, int M, int N, int K) {
    __shared__ __align__(16) unsigned short As[2][256 * 64];
    __shared__ __align__(16) unsigned short Bs[2][128 * 64];
    const int tid = threadIdx.x, lane = tid & 63;
    const int w = tid >> 6;
    const int l15 = lane & 15, l4 = lane >> 4;
    const int wr = w >> 2, wc = w & 3;        // 2 x 4 wave grid
    const int m0 = blockIdx.x * 256, n0 = blockIdx.y * 128;
    f32x4 acc[8][2] = {};

    auto stageA = [&](int buf, int kt, int h) {
#pragma unroll
        for (int i = 0; i < 2; ++i) {
            int p = i * 512 + tid;
            int j = p >> 3;
            int row = h * 64 + (j >> 6) * 128 + (j & 63);
            int sc = p & 7;
            int c = sc ^ (row & 7);
            GLDS16(A + (size_t)(m0 + row) * K + kt * 64 + c * 8,
                   &As[buf][(row * 8 + sc) * 8]);
        }
    };
    auto stageB = [&](int buf, int kt, int h) {
        int j = tid >> 3;                     // 0..63
        int row = h * 16 + (j >> 4) * 32 + (j & 15);   // stripe: bit4 == h
        int sc = tid & 7;
        int c = sc ^ (row & 7);
        GLDS16(Bt + (size_t)(n0 + row) * K + kt * 64 + c * 8,
               &Bs[buf][(row * 8 + sc) * 8]);
    };

    const int NT = K >> 6;
    stageB(0, 0, 0); stageA(0, 0, 0); stageB(0, 0, 1); stageA(0, 0, 1);
    stageB(1, 1, 0); stageA(1, 1, 0);

    bf16x8 bf[2];
    for (int t = 0; t < NT; ++t) {
        const int cur = t & 1, nxt = cur ^ 1;
        if (t == NT - 1) { asm volatile("s_waitcnt vmcnt(0)" ::: "memory"); }
        else             { asm volatile("s_waitcnt vmcnt(3)" ::: "memory"); }
        __builtin_amdgcn_s_barrier();
        __builtin_amdgcn_sched_barrier(0);

#pragma unroll
        for (int q = 0; q < 4; ++q) {
            const int nh = q >> 1, mh = q & 1;
            bf16x8 af[4][2];
#pragma unroll
            for (int mf2 = 0; mf2 < 4; ++mf2)
#pragma unroll
                for (int ks = 0; ks < 2; ++ks) {
                    int row = wr * 128 + (mh * 4 + mf2) * 16 + l15;
                    int ch = (ks * 4 + l4) ^ (row & 7);
                    af[mf2][ks] = *(const bf16x8*)(&As[cur][(row * 8 + ch) * 8]);
                }
            if (mh == 0) {
#pragma unroll
                for (int ks = 0; ks < 2; ++ks) {
                    int row = wc * 32 + nh * 16 + l15;
                    int ch = (ks * 4 + l4) ^ (row & 7);
                    bf[ks] = *(const bf16x8*)(&Bs[cur][(row * 8 + ch) * 8]);
                }
            }
            if (q == 0)      { if (t + 1 < NT) stageB(nxt, t + 1, 1); }
            else if (q == 1) { if (t + 1 < NT) stageA(nxt, t + 1, 1); }
            else if (q == 2) { if (t + 2 < NT) stageB(cur, t + 2, 0); }
            else             { if (t + 2 < NT) stageA(cur, t + 2, 0); }

            __builtin_amdgcn_sched_barrier(0);
            __builtin_amdgcn_s_barrier();
            asm volatile("s_waitcnt lgkmcnt(0)" ::: "memory");
            __builtin_amdgcn_sched_barrier(0);
            __builtin_amdgcn_s_setprio(1);
#pragma unroll
            for (int mf2 = 0; mf2 < 4; ++mf2)
#pragma unroll
                for (int ks = 0; ks < 2; ++ks)
                    acc[mh * 4 + mf2][nh] = __builtin_amdgcn_mfma_f32_16x16x32_bf16(
                        af[mf2][ks], bf[ks], acc[mh * 4 + mf2][nh], 0, 0, 0);
            __builtin_amdgcn_s_setprio(0);
            __builtin_amdgcn_s_barrier();
        }
    }

#pragma unroll
    for (int mf = 0; mf < 8; ++mf) {
        int row = m0 + wr * 128 + mf * 16 + l4 * 4;
#pragma unroll
        for (int nf = 0; nf < 2; ++nf) {
            int col = n0 + wc * 32 + nf * 16 + l15;
            float bv = bias[col];
            if (QVT && col >= H_ + KV_) {
                // V region: write transposed only (flash consumes V^T)
                int vcol = col - (H_ + KV_);
#pragma unroll
                for (int r = 0; r < 4; ++r) {
                    int rr = row + r;
                    int b = rr >> 11, s = rr & 2047;
                    VbT[((size_t)b * KV_ + vcol) * S_ + s] = f2bf(acc[mf][nf][r] + bv);
                }
            } else {
                float sc = (QVT && col < H_) ? SC2F : 1.0f;
#pragma unroll
                for (int r = 0; r < 4; ++r) {
                    float v = (acc[mf][nf][r] + bv) * sc;
                    if (BF16OUT)
                        ((unsigned short*)Cout)[(size_t)(row + r) * N + col] = f2bf(v);
                    else
                        ((float*)Cout)[(size_t)(row + r) * N + col] = v;
                }
            }
        }
    }
}

// ---------------- causal GQA flash attention (R9/R14-proven): QBLK=64, swapped-QK ----------------
// __launch_bounds__(256,4): VGPR 64, zero spill. (256,5) forces VGPR 48 -> scratch
// spill catastrophe (R13: 150us, 255MB spill writes). Keep 4.
__global__ __launch_bounds__(256, 4) void k_flash(
    const unsigned short* __restrict__ QKV,  // [B*S][3072]  Q|K|V  (Q pre-scaled)
    const unsigned short* __restrict__ VT,   // [B][KV][S]
    unsigned short* __restrict__ Oa,         // [B*S][H]
    unsigned short* __restrict__ part1,      // [512][64][128] bf16 chunk1 partial O
    float* __restrict__ mlbuf) {             // [1024][64][2] f32 (m,l) per chunk
    __shared__ __align__(16) unsigned short Ks[64 * 128];    // K tile, chunk-swizzled
    __shared__ __align__(16) unsigned short Vs[128 * 64];    // V^T tile, chunk-swizzled
    const int tid = threadIdx.x, lane = tid & 63, w = tid >> 6;
    const int l15 = lane & 15, l4 = lane >> 4;
    const int bid = blockIdx.x;               // 0..1535
    const int xcd = bid & 7, idx = bid >> 3;  // 192 jobs per XCD
    const int bh = xcd * 4 + (idx & 3);       // 4 heads per XCD = one (b,g)
    const int jidx = idx >> 2;                // 0..47, descending work
    const int b = bh >> 4, nh = bh & 15, g = nh >> 2;

    int qt, t0, t1, mode;                     // mode: 0 full, 1 chunk0, 2 chunk1
    if (jidx < 16) { qt = 16 + jidx; t0 = 0; t1 = 16; mode = 1; }
    else {
        int k = jidx - 16, j = k >> 1;
        if ((k & 1) == 0) { qt = 31 - j; t0 = 16; t1 = qt + 1; mode = 2; }
        else              { qt = 15 - j; t0 = 0;  t1 = qt + 1; mode = 0; }
    }
    const int qbase = qt * 64 + w * 16;       // wave's 16 q-rows; lane's q = qbase + l15

    const unsigned short* kgbase = QKV + (size_t)b * S_ * HQKV + H_ + g * HD_;
    const unsigned short* vgbase = VT + ((size_t)b * KV_ + g * HD_) * S_;

    auto issueK = [&](int kt) {
        const int kv0 = kt * 64;
#pragma unroll
        for (int i = 0; i < 4; ++i) {
            int p = i * 256 + tid;
            int row = p >> 4, c = (p & 15) ^ (row & 15);
            GLDS16(kgbase + (size_t)(kv0 + row) * HQKV + c * 8, &Ks[(i * 256 + w * 64) * 8]);
        }
    };
    auto issueV = [&](int kt) {
        const int kv0 = kt * 64;
#pragma unroll
        for (int i = 0; i < 4; ++i) {
            int p = i * 256 + tid;
            int row = p >> 3, c = (p & 7) ^ (row & 7);
            GLDS16(vgbase + (size_t)row * S_ + kv0 + c * 8, &Vs[(i * 256 + w * 64) * 8]);
        }
    };

    bf16x8 qf[4];
#pragma unroll
    for (int kb = 0; kb < 4; ++kb)
        qf[kb] = *(const bf16x8*)(QKV + (size_t)(b * S_ + qbase + l15) * HQKV +
                                  nh * HD_ + kb * 32 + l4 * 8);

    f32x4 o[8] = {};                          // O^T: o[nc][r] = O[d=nc*16+l4*4+r][q=l15]
    float m_r = -1e30f, l_r = 0.f;

    const int src0 = l15 + 16 * ((2 * l4) & 3);
    const int src1 = l15 + 16 * ((2 * l4 + 1) & 3);
    const bool hsel = ((l4 >> 1) & 1) != 0;

    issueK(t0);
    issueV(t0);

    for (int kt = t0; kt < t1; ++kt) {
        const int kv0 = kt * 64;
        asm volatile("s_waitcnt vmcnt(4)" ::: "memory");
        __builtin_amdgcn_s_barrier();
        __builtin_amdgcn_sched_barrier(0);

        // S^T = K Q^T
        f32x4 s[4] = {};
#pragma unroll
        for (int kb = 0; kb < 4; ++kb) {
            bf16x8 kf[4];
#pragma unroll
            for (int n = 0; n < 4; ++n) {
                int row = n * 16 + l15;
                int sl = (kb * 4 + l4) ^ (row & 15);
                kf[n] = *(const bf16x8*)(&Ks[(row * 16 + sl) * 8]);
            }
            __builtin_amdgcn_s_setprio(1);
#pragma unroll
            for (int n = 0; n < 4; ++n)
                s[n] = __builtin_amdgcn_mfma_f32_16x16x32_bf16(kf[n], qf[kb], s[n], 0, 0, 0);
            __builtin_amdgcn_s_setprio(0);
        }
        if (kv0 + 63 > qbase) {
            const int qrow = qbase + l15;
#pragma unroll
            for (int n = 0; n < 4; ++n)
#pragma unroll
                for (int r = 0; r < 4; ++r) {
                    int kcol = kv0 + n * 16 + l4 * 4 + r;
                    if (kcol > qrow) s[n][r] = -1e30f;
                }
        }
        float pmax = s[0][0];
#pragma unroll
        for (int n = 0; n < 4; ++n)
#pragma unroll
            for (int r = 0; r < 4; ++r) pmax = fmaxf(pmax, s[n][r]);
        pmax = fmaxf(pmax, __shfl_xor(pmax, 16));
        pmax = fmaxf(pmax, __shfl_xor(pmax, 32));
        if (__any(pmax > m_r + 8.0f)) {
            float mn = fmaxf(m_r, pmax);
            float sf = exp2f(m_r - mn);
            m_r = mn;
            l_r *= sf;
#pragma unroll
            for (int nc = 0; nc < 8; ++nc) {
                f32x4 t = o[nc];
                t[0] *= sf; t[1] *= sf; t[2] *= sf; t[3] *= sf;
                o[nc] = t;
            }
        }
        float rsum = 0.f;
#pragma unroll
        for (int n = 0; n < 4; ++n)
#pragma unroll
            for (int r = 0; r < 4; ++r) {
                float p = exp2f(s[n][r] - m_r);
                s[n][r] = p;
                rsum += p;
            }
        rsum += __shfl_xor(rsum, 16);
        rsum += __shfl_xor(rsum, 32);
        l_r += rsum;

        unsigned plo[4], phi[4];
#pragma unroll
        for (int n = 0; n < 4; ++n) {
            plo[n] = cvtpk(s[n][0], s[n][1]);
            phi[n] = cvtpk(s[n][2], s[n][3]);
        }

        asm volatile("s_waitcnt vmcnt(0)" ::: "memory");
        __builtin_amdgcn_s_barrier();
        __builtin_amdgcn_sched_barrier(0);
        if (kt + 1 < t1) issueK(kt + 1);

#pragma unroll
        for (int kb = 0; kb < 2; ++kb) {
            const int n0i = 2 * kb, n1i = 2 * kb + 1;
            unsigned a0, a1, w0, w1, w2, w3;
            a0 = __shfl((int)plo[n0i], src0); a1 = __shfl((int)plo[n1i], src0); w0 = hsel ? a1 : a0;
            a0 = __shfl((int)phi[n0i], src0); a1 = __shfl((int)phi[n1i], src0); w1 = hsel ? a1 : a0;
            a0 = __shfl((int)plo[n0i], src1); a1 = __shfl((int)plo[n1i], src1); w2 = hsel ? a1 : a0;
            a0 = __shfl((int)phi[n0i], src1); a1 = __shfl((int)phi[n1i], src1); w3 = hsel ? a1 : a0;
            int4 pw = make_int4((int)w0, (int)w1, (int)w2, (int)w3);
            bf16x8 pf = *(bf16x8*)&pw;
            __builtin_amdgcn_s_setprio(1);
#pragma unroll
            for (int nc = 0; nc < 8; ++nc) {
                int row = nc * 16 + l15;
                int sl = (kb * 4 + l4) ^ (row & 7);
                bf16x8 vf = *(const bf16x8*)(&Vs[(row * 8 + sl) * 8]);
                o[nc] = __builtin_amdgcn_mfma_f32_16x16x32_bf16(vf, pf, o[nc], 0, 0, 0);
            }
            __builtin_amdgcn_s_setprio(0);
        }

        __builtin_amdgcn_s_barrier();
        __builtin_amdgcn_sched_barrier(0);
        if (kt + 1 < t1) issueV(kt + 1);
    }

    const int qrow = qbase + l15;
    if (mode == 0) {
        float inv = 1.0f / l_r;
        size_t base = (size_t)(b * S_ + qrow) * H_ + nh * HD_ + l4 * 4;
#pragma unroll
        for (int nc = 0; nc < 8; ++nc) {
            uint2 pk;
            pk.x = cvtpk(o[nc][0] * inv, o[nc][1] * inv);
            pk.y = cvtpk(o[nc][2] * inv, o[nc][3] * inv);
            *(uint2*)(Oa + base + nc * 16) = pk;
        }
    } else {
        const int base = bh * 16 + (qt - 16);
        const int c = (mode == 1) ? 0 : 1;
        float* mlrec = mlbuf + (size_t)(base * 2 + c) * 64 * 2;
        if (l4 == 0) {
            int row = w * 16 + l15;
            mlrec[row * 2 + 0] = m_r;
            mlrec[row * 2 + 1] = l_r;
        }
        if (mode == 1) {
            size_t ob = (size_t)(b * S_ + qrow) * H_ + nh * HD_ + l4 * 4;
#pragma unroll
            for (int nc = 0; nc < 8; ++nc) {
                uint2 pk;
                pk.x = cvtpk(o[nc][0], o[nc][1]);
                pk.y = cvtpk(o[nc][2], o[nc][3]);
                *(uint2*)(Oa + ob + nc * 16) = pk;
            }
        } else {
            size_t pb = ((size_t)base * 64 + w * 16 + l15) * 128 + l4 * 4;
#pragma unroll
            for (int nc = 0; nc < 8; ++nc) {
                uint2 pk;
                pk.x = cvtpk(o[nc][0], o[nc][1]);
                pk.y = cvtpk(o[nc][2], o[nc][3]);
                *(uint2*)(part1 + pb + nc * 16) = pk;
            }
        }
    }
}

// ---------------- combine split-K partials ----------------
__global__ __launch_bounds__(256) void k_combine(
    const float* __restrict__ mlbuf, const unsigned short* __restrict__ part1,
    unsigned short* __restrict__ Oa) {
    int rec = blockIdx.x;                 // 0..511: bh*16 + (qt-16)
    int bh = rec >> 4, qt = 16 + (rec & 15);
    int b = bh >> 4, nh = bh & 15;
    int row = threadIdx.x >> 2;           // 0..63
    int dseg = (threadIdx.x & 3) * 32;
    const float* ml0 = mlbuf + (size_t)(rec * 2 + 0) * 128;
    const float* ml1 = mlbuf + (size_t)(rec * 2 + 1) * 128;
    float m0 = ml0[row * 2], l0 = ml0[row * 2 + 1];
    float m1 = ml1[row * 2], l1 = ml1[row * 2 + 1];
    float M = fmaxf(m0, m1);
    float a0 = exp2f(m0 - M), a1 = exp2f(m1 - M);
    float L = a0 * l0 + a1 * l1;
    float s0 = a0 / L, s1 = a1 / L;
    size_t ob = ((size_t)(b * S_) + qt * 64 + row) * H_ + nh * HD_ + dseg;
    const unsigned short* p1 = part1 + ((size_t)rec * 64 + row) * 128 + dseg;
#pragma unroll
    for (int i = 0; i < 4; ++i) {
        bf16x8 v0 = *(const bf16x8*)(Oa + ob + i * 8);
        bf16x8 v1 = *(const bf16x8*)(p1 + i * 8);
        bf16x8 oo;
#pragma unroll
        for (int e = 0; e < 8; ++e)
            oo[e] = (short)f2bf(bf2f((unsigned short)v0[e]) * s0 +
                                bf2f((unsigned short)v1[e]) * s1);
        *(bf16x8*)(Oa + ob + i * 8) = oo;
    }
}

// ---------------- launch ----------------
extern "C" void kernel_launch(void* const* d_in, const int* in_sizes, int n_in,
                              void* d_out, int out_size, void* d_ws, size_t ws_size,
                              hipStream_t stream) {
    const float* X  = (const float*)d_in[0];
    const float* Wq = (const float*)d_in[1];
    const float* bq = (const float*)d_in[2];
    const float* Wk = (const float*)d_in[3];
    const float* bk = (const float*)d_in[4];
    const float* Wv = (const float*)d_in[5];
    const float* bv = (const float*)d_in[6];
    const float* Wo = (const float*)d_in[7];
    const float* bo = (const float*)d_in[8];
    float* out = (float*)d_out;

    if (ws_size < 80000000) return;
    char* ws = (char*)d_ws;
    unsigned short* Xb    = (unsigned short*)(ws);              // 16.78 MB; reused as AOb
    unsigned short* WqkvT = (unsigned short*)(ws + 16777216);   // [3072][2048] 12.58 MB
    unsigned short* WoT   = (unsigned short*)(ws + 29360128);   // 8.39 MB
    unsigned short* QKV   = (unsigned short*)(ws + 37748736);   // [4096][3072] 25.17 MB (V region unused)
    unsigned short* VbT   = (unsigned short*)(ws + 62914560);   // 4.19 MB
    unsigned short* part1 = (unsigned short*)(ws + 67108864);   // 512*64*128 bf16 = 8.39 MB
    float*          mlbuf = (float*)(ws + 75497472);            // 1024*64*2 f32 = 512 KB
    float*          bqkv  = (float*)(ws + 76021760);            // 12 KB
    unsigned short* AOb   = Xb;                                 // Xb dead after QKV GEMM

    // fused prep: X cvt + Wqkv transpose + Wo transpose + bias concat (one dispatch)
    k_prep<<<dim3(18444), 256, 0, stream>>>(X, Wq, Wk, Wv, Wo, bq, bk, bv,
                                            Xb, WqkvT, WoT, bqkv);

    // fused QKV projection: 256x128 8-phase engine, grid 16x24 = 384 blocks.
    // V-blocks (blockIdx.y >= 20) launch last -> run in the half-idle round 2.
    k_gemm256x128<true, true><<<dim3(16, 24), 512, 0, stream>>>(
        Xb, WqkvT, bqkv, QKV, VbT, 4096, HQKV, 2048);

    k_flash<<<dim3(1536), 256, 0, stream>>>(QKV, VbT, AOb, part1, mlbuf);
    k_combine<<<dim3(512), 256, 0, stream>>>(mlbuf, part1, AOb);

    // O-projection: 256x128 8-phase, grid 16x16 = 256 blocks (full chip)
    k_gemm256x128<false, false><<<dim3(16, 16), 512, 0, stream>>>(
        AOb, WoT, bo, out, nullptr, 4096, 2048, 2048);
}

// Round 16
// 213.445 us; speedup vs baseline: 1.1192x; 1.1192x over previous
//
#include <hip/hip_runtime.h>

// Problem constants
#define B_   2
#define S_   2048
#define H_   2048
#define NH_  16
#define G_   4
#define HD_  128
#define KV_  512
#define HQKV 3072   // fused Q|K|V output width

typedef __attribute__((ext_vector_type(8))) short bf16x8;
typedef __attribute__((ext_vector_type(4))) float f32x4;

__device__ __forceinline__ unsigned short f2bf(float f) {
    unsigned u = __float_as_uint(f);
    u += 0x7fff + ((u >> 16) & 1);   // RNE
    return (unsigned short)(u >> 16);
}
__device__ __forceinline__ float bf2f(unsigned short s) {
    return __uint_as_float(((unsigned)s) << 16);
}
// D.lo = bf16(a), D.hi = bf16(b)  (RNE)
__device__ __forceinline__ unsigned cvtpk(float a, float b) {
    unsigned r;
    asm volatile("v_cvt_pk_bf16_f32 %0, %1, %2" : "=v"(r) : "v"(a), "v"(b));
    return r;
}

#define GLDS16(gsrc, ldst)                                                            \
    __builtin_amdgcn_global_load_lds(                                                 \
        (const __attribute__((address_space(1))) void*)(gsrc),                        \
        (__attribute__((address_space(3))) void*)(ldst), 16, 0, 0)

// 1/sqrt(128) * log2(e): folded into Q columns of the QKV GEMM epilogue
#define SC2F (0.08838834764831843f * 1.4426950408889634f)

// ---------------- fused prep: cvt X | transpose Wq/Wk/Wv | transpose Wo | bias ----------------
__global__ __launch_bounds__(256) void k_prep(
    const float* __restrict__ X,  const float* __restrict__ Wq,
    const float* __restrict__ Wk, const float* __restrict__ Wv,
    const float* __restrict__ Wo, const float* __restrict__ bq,
    const float* __restrict__ bk, const float* __restrict__ bv,
    unsigned short* __restrict__ Xb, unsigned short* __restrict__ WqkvT,
    unsigned short* __restrict__ WoT, float* __restrict__ bqkv) {
    __shared__ float t[32][33];
    const int bid = blockIdx.x, tid = threadIdx.x;
    if (bid < 8192) {                       // X fp32 -> bf16 (2,097,152 float4s)
        int i = bid * 256 + tid;
        float4 v = ((const float4*)X)[i];
        ushort4 o;
        o.x = f2bf(v.x); o.y = f2bf(v.y); o.z = f2bf(v.z); o.w = f2bf(v.w);
        ((ushort4*)Xb)[i] = o;
        return;
    }
    const int tx = tid & 31, ty = tid >> 5;  // 32 x 8
    if (bid < 14336) {                      // Wq|Wk|Wv -> WqkvT [3072][2048]
        int idx = bid - 8192;
        int n0g = (idx % 96) * 32, h0 = (idx / 96) * 32;
        const float* src; int C, n0l;
        if (n0g < H_)            { src = Wq; C = H_;  n0l = n0g; }
        else if (n0g < H_ + KV_) { src = Wk; C = KV_; n0l = n0g - H_; }
        else                     { src = Wv; C = KV_; n0l = n0g - H_ - KV_; }
#pragma unroll
        for (int i = 0; i < 4; ++i)
            t[ty + i*8][tx] = src[(size_t)(h0 + ty + i*8) * C + n0l + tx];
        __syncthreads();
#pragma unroll
        for (int i = 0; i < 4; ++i)
            WqkvT[(size_t)(n0g + ty + i*8) * H_ + h0 + tx] = f2bf(t[tx][ty + i*8]);
        return;
    }
    if (bid < 18432) {                      // Wo -> WoT [2048][2048]
        int idx = bid - 14336;
        int c0 = (idx % 64) * 32, r0 = (idx / 64) * 32;
#pragma unroll
        for (int i = 0; i < 4; ++i)
            t[ty + i*8][tx] = Wo[(size_t)(r0 + ty + i*8) * H_ + c0 + tx];
        __syncthreads();
#pragma unroll
        for (int i = 0; i < 4; ++i)
            WoT[(size_t)(c0 + ty + i*8) * H_ + r0 + tx] = f2bf(t[tx][ty + i*8]);
        return;
    }
    int i = (bid - 18432) * 256 + tid;      // bias concat [3072]
    if (i < HQKV)
        bqkv[i] = (i < H_) ? bq[i] : (i < H_ + KV_ ? bk[i - H_] : bv[i - H_ - KV_]);
}

// ---------------- 256x256 8-phase bf16 GEMM (R14-validated) + fused V^T epilogue ----------------
__global__ __launch_bounds__(512, 2) void k_gemm256(
    const unsigned short* __restrict__ A, const unsigned short* __restrict__ Bt,
    const float* __restrict__ bias, unsigned short* __restrict__ Cout,
    unsigned short* __restrict__ VbT, int M, int N, int K) {
    __shared__ __align__(16) unsigned short As[2][256 * 64];
    __shared__ __align__(16) unsigned short Bs[2][256 * 64];
    const int tid = threadIdx.x, lane = tid & 63;
    const int w = tid >> 6;
    const int l15 = lane & 15, l4 = lane >> 4;
    const int wr = w >> 2, wc = w & 3;        // 2 x 4 wave grid
    const int m0 = blockIdx.x * 256, n0 = blockIdx.y * 256;
    f32x4 acc[8][4] = {};

    auto stageA = [&](int buf, int kt, int h) {
#pragma unroll
        for (int i = 0; i < 2; ++i) {
            int p = i * 512 + tid;
            int j = p >> 3;
            int row = h * 64 + (j >> 6) * 128 + (j & 63);
            int sc = p & 7;
            int c = sc ^ (row & 7);
            GLDS16(A + (size_t)(m0 + row) * K + kt * 64 + c * 8,
                   &As[buf][(row * 8 + sc) * 8]);
        }
    };
    auto stageB = [&](int buf, int kt, int h) {
#pragma unroll
        for (int i = 0; i < 2; ++i) {
            int p = i * 512 + tid;
            int j = p >> 3;
            int row = h * 32 + (j >> 5) * 64 + (j & 31);
            int sc = p & 7;
            int c = sc ^ (row & 7);
            GLDS16(Bt + (size_t)(n0 + row) * K + kt * 64 + c * 8,
                   &Bs[buf][(row * 8 + sc) * 8]);
        }
    };

    const int NT = K >> 6;
    stageB(0, 0, 0); stageA(0, 0, 0); stageB(0, 0, 1); stageA(0, 0, 1);
    stageB(1, 1, 0); stageA(1, 1, 0);

    bf16x8 bf[2][2];
    for (int t = 0; t < NT; ++t) {
        const int cur = t & 1, nxt = cur ^ 1;
        if (t == NT - 1) { asm volatile("s_waitcnt vmcnt(0)" ::: "memory"); }
        else             { asm volatile("s_waitcnt vmcnt(4)" ::: "memory"); }
        __builtin_amdgcn_s_barrier();
        __builtin_amdgcn_sched_barrier(0);

#pragma unroll
        for (int q = 0; q < 4; ++q) {
            const int nh = q >> 1, mh = q & 1;
            bf16x8 af[4][2];
#pragma unroll
            for (int mf2 = 0; mf2 < 4; ++mf2)
#pragma unroll
                for (int ks = 0; ks < 2; ++ks) {
                    int row = wr * 128 + (mh * 4 + mf2) * 16 + l15;
                    int ch = (ks * 4 + l4) ^ (row & 7);
                    af[mf2][ks] = *(const bf16x8*)(&As[cur][(row * 8 + ch) * 8]);
                }
            if (mh == 0) {
#pragma unroll
                for (int nf2 = 0; nf2 < 2; ++nf2)
#pragma unroll
                    for (int ks = 0; ks < 2; ++ks) {
                        int row = wc * 64 + (nh * 2 + nf2) * 16 + l15;
                        int ch = (ks * 4 + l4) ^ (row & 7);
                        bf[nf2][ks] = *(const bf16x8*)(&Bs[cur][(row * 8 + ch) * 8]);
                    }
            }
            if (q == 0)      { if (t + 1 < NT) stageB(nxt, t + 1, 1); }
            else if (q == 1) { if (t + 1 < NT) stageA(nxt, t + 1, 1); }
            else if (q == 2) { if (t + 2 < NT) stageB(cur, t + 2, 0); }
            else             { if (t + 2 < NT) stageA(cur, t + 2, 0); }

            __builtin_amdgcn_sched_barrier(0);
            __builtin_amdgcn_s_barrier();
            asm volatile("s_waitcnt lgkmcnt(0)" ::: "memory");
            __builtin_amdgcn_sched_barrier(0);
            __builtin_amdgcn_s_setprio(1);
#pragma unroll
            for (int mf2 = 0; mf2 < 4; ++mf2)
#pragma unroll
                for (int nf2 = 0; nf2 < 2; ++nf2)
#pragma unroll
                    for (int ks = 0; ks < 2; ++ks)
                        acc[mh * 4 + mf2][nh * 2 + nf2] = __builtin_amdgcn_mfma_f32_16x16x32_bf16(
                            af[mf2][ks], bf[nf2][ks], acc[mh * 4 + mf2][nh * 2 + nf2], 0, 0, 0);
            __builtin_amdgcn_s_setprio(0);
            __builtin_amdgcn_s_barrier();
        }
    }

#pragma unroll
    for (int mf = 0; mf < 8; ++mf) {
        int row = m0 + wr * 128 + mf * 16 + l4 * 4;
#pragma unroll
        for (int nf = 0; nf < 4; ++nf) {
            int col = n0 + wc * 64 + nf * 16 + l15;
            float bv = bias[col];
            if (col >= H_ + KV_) {
                // V region: write transposed only (flash consumes V^T)
                int vcol = col - (H_ + KV_);
#pragma unroll
                for (int r = 0; r < 4; ++r) {
                    int rr = row + r;
                    int b = rr >> 11, s = rr & 2047;
                    VbT[((size_t)b * KV_ + vcol) * S_ + s] = f2bf(acc[mf][nf][r] + bv);
                }
            } else {
                float sc = (col < H_) ? SC2F : 1.0f;
#pragma unroll
                for (int r = 0; r < 4; ++r) {
                    float v = (acc[mf][nf][r] + bv) * sc;
                    Cout[(size_t)(row + r) * N + col] = f2bf(v);
                }
            }
        }
    }
}

// ---------------- 256x128 8-phase bf16 GEMM (validated R11/R14, O-proj only) ----------------
template <bool BF16OUT>
__global__ __launch_bounds__(512, 1) void k_gemm256x128(
    const unsigned short* __restrict__ A, const unsigned short* __restrict__ Bt,
    const float* __restrict__ bias, void* __restrict__ Cout, int M, int N, int K) {
    __shared__ __align__(16) unsigned short As[2][256 * 64];
    __shared__ __align__(16) unsigned short Bs[2][128 * 64];
    const int tid = threadIdx.x, lane = tid & 63;
    const int w = tid >> 6;
    const int l15 = lane & 15, l4 = lane >> 4;
    const int wr = w >> 2, wc = w & 3;        // 2 x 4 wave grid
    const int m0 = blockIdx.x * 256, n0 = blockIdx.y * 128;
    f32x4 acc[8][2] = {};

    auto stageA = [&](int buf, int kt, int h) {
#pragma unroll
        for (int i = 0; i < 2; ++i) {
            int p = i * 512 + tid;
            int j = p >> 3;
            int row = h * 64 + (j >> 6) * 128 + (j & 63);
            int sc = p & 7;
            int c = sc ^ (row & 7);
            GLDS16(A + (size_t)(m0 + row) * K + kt * 64 + c * 8,
                   &As[buf][(row * 8 + sc) * 8]);
        }
    };
    auto stageB = [&](int buf, int kt, int h) {
        int j = tid >> 3;                     // 0..63
        int row = h * 16 + (j >> 4) * 32 + (j & 15);   // stripe: bit4 == h
        int sc = tid & 7;
        int c = sc ^ (row & 7);
        GLDS16(Bt + (size_t)(n0 + row) * K + kt * 64 + c * 8,
               &Bs[buf][(row * 8 + sc) * 8]);
    };

    const int NT = K >> 6;
    stageB(0, 0, 0); stageA(0, 0, 0); stageB(0, 0, 1); stageA(0, 0, 1);
    stageB(1, 1, 0); stageA(1, 1, 0);

    bf16x8 bf[2];
    for (int t = 0; t < NT; ++t) {
        const int cur = t & 1, nxt = cur ^ 1;
        if (t == NT - 1) { asm volatile("s_waitcnt vmcnt(0)" ::: "memory"); }
        else             { asm volatile("s_waitcnt vmcnt(3)" ::: "memory"); }
        __builtin_amdgcn_s_barrier();
        __builtin_amdgcn_sched_barrier(0);

#pragma unroll
        for (int q = 0; q < 4; ++q) {
            const int nh = q >> 1, mh = q & 1;
            bf16x8 af[4][2];
#pragma unroll
            for (int mf2 = 0; mf2 < 4; ++mf2)
#pragma unroll
                for (int ks = 0; ks < 2; ++ks) {
                    int row = wr * 128 + (mh * 4 + mf2) * 16 + l15;
                    int ch = (ks * 4 + l4) ^ (row & 7);
                    af[mf2][ks] = *(const bf16x8*)(&As[cur][(row * 8 + ch) * 8]);
                }
            if (mh == 0) {
#pragma unroll
                for (int ks = 0; ks < 2; ++ks) {
                    int row = wc * 32 + nh * 16 + l15;
                    int ch = (ks * 4 + l4) ^ (row & 7);
                    bf[ks] = *(const bf16x8*)(&Bs[cur][(row * 8 + ch) * 8]);
                }
            }
            if (q == 0)      { if (t + 1 < NT) stageB(nxt, t + 1, 1); }
            else if (q == 1) { if (t + 1 < NT) stageA(nxt, t + 1, 1); }
            else if (q == 2) { if (t + 2 < NT) stageB(cur, t + 2, 0); }
            else             { if (t + 2 < NT) stageA(cur, t + 2, 0); }

            __builtin_amdgcn_sched_barrier(0);
            __builtin_amdgcn_s_barrier();
            asm volatile("s_waitcnt lgkmcnt(0)" ::: "memory");
            __builtin_amdgcn_sched_barrier(0);
            __builtin_amdgcn_s_setprio(1);
#pragma unroll
            for (int mf2 = 0; mf2 < 4; ++mf2)
#pragma unroll
                for (int ks = 0; ks < 2; ++ks)
                    acc[mh * 4 + mf2][nh] = __builtin_amdgcn_mfma_f32_16x16x32_bf16(
                        af[mf2][ks], bf[ks], acc[mh * 4 + mf2][nh], 0, 0, 0);
            __builtin_amdgcn_s_setprio(0);
            __builtin_amdgcn_s_barrier();
        }
    }

#pragma unroll
    for (int mf = 0; mf < 8; ++mf) {
        int row = m0 + wr * 128 + mf * 16 + l4 * 4;
#pragma unroll
        for (int nf = 0; nf < 2; ++nf) {
            int col = n0 + wc * 32 + nf * 16 + l15;
            float bv = bias[col];
#pragma unroll
            for (int r = 0; r < 4; ++r) {
                float v = acc[mf][nf][r] + bv;
                if (BF16OUT)
                    ((unsigned short*)Cout)[(size_t)(row + r) * N + col] = f2bf(v);
                else
                    ((float*)Cout)[(size_t)(row + r) * N + col] = v;
            }
        }
    }
}

// ---------------- causal GQA flash attention: balanced 1024-block schedule ----------------
// 32 jobs per bh, each 16-17 k-tiles -> grid 1024 = exactly 4 blocks/CU (LDS cap),
// single fully-resident round. Jobs: jidx 0..15 = chunk0 (qt=16+jidx, 16 tiles);
// jidx 16..23 = chunk1 pair {31-j, 16+j} (17 tiles); jidx 24..31 = full pair
// {15-j, j} (17 tiles). Pair blocks run 2 segments of the proven pipeline; the
// final loop-iteration barrier synchronizes LDS reuse across segments.
// __launch_bounds__(256,4): VGPR 64, zero spill ((256,5) spills: R13).
__global__ __launch_bounds__(256, 4) void k_flash(
    const unsigned short* __restrict__ QKV,  // [B*S][3072]  Q|K|V  (Q pre-scaled)
    const unsigned short* __restrict__ VT,   // [B][KV][S]
    unsigned short* __restrict__ Oa,         // [B*S][H]
    unsigned short* __restrict__ part1,      // [512][64][128] bf16 chunk1 partial O
    float* __restrict__ mlbuf) {             // [1024][64][2] f32 (m,l) per chunk
    __shared__ __align__(16) unsigned short Ks[64 * 128];    // K tile, chunk-swizzled
    __shared__ __align__(16) unsigned short Vs[128 * 64];    // V^T tile, chunk-swizzled
    const int tid = threadIdx.x, lane = tid & 63, w = tid >> 6;
    const int l15 = lane & 15, l4 = lane >> 4;
    const int bid = blockIdx.x;               // 0..1023
    const int xcd = bid & 7, idx = bid >> 3;  // 128 jobs per XCD
    const int bh = xcd * 4 + (idx & 3);       // 4 heads per XCD = one (b,g)
    const int jidx = idx >> 2;                // 0..31
    const int b = bh >> 4, nh = bh & 15, g = nh >> 2;

    const unsigned short* kgbase = QKV + (size_t)b * S_ * HQKV + H_ + g * HD_;
    const unsigned short* vgbase = VT + ((size_t)b * KV_ + g * HD_) * S_;

    auto issueK = [&](int kt) {
        const int kv0 = kt * 64;
#pragma unroll
        for (int i = 0; i < 4; ++i) {
            int p = i * 256 + tid;
            int row = p >> 4, c = (p & 15) ^ (row & 15);
            GLDS16(kgbase + (size_t)(kv0 + row) * HQKV + c * 8, &Ks[(i * 256 + w * 64) * 8]);
        }
    };
    auto issueV = [&](int kt) {
        const int kv0 = kt * 64;
#pragma unroll
        for (int i = 0; i < 4; ++i) {
            int p = i * 256 + tid;
            int row = p >> 3, c = (p & 7) ^ (row & 7);
            GLDS16(vgbase + (size_t)row * S_ + kv0 + c * 8, &Vs[(i * 256 + w * 64) * 8]);
        }
    };

    const int src0 = l15 + 16 * ((2 * l4) & 3);
    const int src1 = l15 + 16 * ((2 * l4 + 1) & 3);
    const bool hsel = ((l4 >> 1) & 1) != 0;

    const int nseg = (jidx < 16) ? 1 : 2;
    for (int seg = 0; seg < nseg; ++seg) {
        int qt, t0, t1, mode;                 // mode: 0 full, 1 chunk0, 2 chunk1
        if (jidx < 16)      { qt = 16 + jidx; t0 = 0; t1 = 16; mode = 1; }
        else if (jidx < 24) { int j = jidx - 16; qt = seg ? (16 + j) : (31 - j);
                              t0 = 16; t1 = qt + 1; mode = 2; }
        else                { int j = jidx - 24; qt = seg ? j : (15 - j);
                              t0 = 0; t1 = qt + 1; mode = 0; }
        const int qbase = qt * 64 + w * 16;   // wave's 16 q-rows; lane's q = qbase + l15

        bf16x8 qf[4];
#pragma unroll
        for (int kb = 0; kb < 4; ++kb)
            qf[kb] = *(const bf16x8*)(QKV + (size_t)(b * S_ + qbase + l15) * HQKV +
                                      nh * HD_ + kb * 32 + l4 * 8);

        f32x4 o[8] = {};                      // O^T: o[nc][r] = O[d=nc*16+l4*4+r][q=l15]
        float m_r = -1e30f, l_r = 0.f;

        issueK(t0);
        issueV(t0);

        for (int kt = t0; kt < t1; ++kt) {
            const int kv0 = kt * 64;
            asm volatile("s_waitcnt vmcnt(4)" ::: "memory");
            __builtin_amdgcn_s_barrier();
            __builtin_amdgcn_sched_barrier(0);

            // S^T = K Q^T
            f32x4 s[4] = {};
#pragma unroll
            for (int kb = 0; kb < 4; ++kb) {
                bf16x8 kf[4];
#pragma unroll
                for (int n = 0; n < 4; ++n) {
                    int row = n * 16 + l15;
                    int sl = (kb * 4 + l4) ^ (row & 15);
                    kf[n] = *(const bf16x8*)(&Ks[(row * 16 + sl) * 8]);
                }
                __builtin_amdgcn_s_setprio(1);
#pragma unroll
                for (int n = 0; n < 4; ++n)
                    s[n] = __builtin_amdgcn_mfma_f32_16x16x32_bf16(kf[n], qf[kb], s[n], 0, 0, 0);
                __builtin_amdgcn_s_setprio(0);
            }
            if (kv0 + 63 > qbase) {
                const int qrow = qbase + l15;
#pragma unroll
                for (int n = 0; n < 4; ++n)
#pragma unroll
                    for (int r = 0; r < 4; ++r) {
                        int kcol = kv0 + n * 16 + l4 * 4 + r;
                        if (kcol > qrow) s[n][r] = -1e30f;
                    }
            }
            float pmax = s[0][0];
#pragma unroll
            for (int n = 0; n < 4; ++n)
#pragma unroll
                for (int r = 0; r < 4; ++r) pmax = fmaxf(pmax, s[n][r]);
            pmax = fmaxf(pmax, __shfl_xor(pmax, 16));
            pmax = fmaxf(pmax, __shfl_xor(pmax, 32));
            if (__any(pmax > m_r + 8.0f)) {
                float mn = fmaxf(m_r, pmax);
                float sf = exp2f(m_r - mn);
                m_r = mn;
                l_r *= sf;
#pragma unroll
                for (int nc = 0; nc < 8; ++nc) {
                    f32x4 t = o[nc];
                    t[0] *= sf; t[1] *= sf; t[2] *= sf; t[3] *= sf;
                    o[nc] = t;
                }
            }
            float rsum = 0.f;
#pragma unroll
            for (int n = 0; n < 4; ++n)
#pragma unroll
                for (int r = 0; r < 4; ++r) {
                    float p = exp2f(s[n][r] - m_r);
                    s[n][r] = p;
                    rsum += p;
                }
            rsum += __shfl_xor(rsum, 16);
            rsum += __shfl_xor(rsum, 32);
            l_r += rsum;

            unsigned plo[4], phi[4];
#pragma unroll
            for (int n = 0; n < 4; ++n) {
                plo[n] = cvtpk(s[n][0], s[n][1]);
                phi[n] = cvtpk(s[n][2], s[n][3]);
            }

            asm volatile("s_waitcnt vmcnt(0)" ::: "memory");
            __builtin_amdgcn_s_barrier();
            __builtin_amdgcn_sched_barrier(0);
            if (kt + 1 < t1) issueK(kt + 1);

#pragma unroll
            for (int kb = 0; kb < 2; ++kb) {
                const int n0i = 2 * kb, n1i = 2 * kb + 1;
                unsigned a0, a1, w0, w1, w2, w3;
                a0 = __shfl((int)plo[n0i], src0); a1 = __shfl((int)plo[n1i], src0); w0 = hsel ? a1 : a0;
                a0 = __shfl((int)phi[n0i], src0); a1 = __shfl((int)phi[n1i], src0); w1 = hsel ? a1 : a0;
                a0 = __shfl((int)plo[n0i], src1); a1 = __shfl((int)plo[n1i], src1); w2 = hsel ? a1 : a0;
                a0 = __shfl((int)phi[n0i], src1); a1 = __shfl((int)phi[n1i], src1); w3 = hsel ? a1 : a0;
                int4 pw = make_int4((int)w0, (int)w1, (int)w2, (int)w3);
                bf16x8 pf = *(bf16x8*)&pw;
                __builtin_amdgcn_s_setprio(1);
#pragma unroll
                for (int nc = 0; nc < 8; ++nc) {
                    int row = nc * 16 + l15;
                    int sl = (kb * 4 + l4) ^ (row & 7);
                    bf16x8 vf = *(const bf16x8*)(&Vs[(row * 8 + sl) * 8]);
                    o[nc] = __builtin_amdgcn_mfma_f32_16x16x32_bf16(vf, pf, o[nc], 0, 0, 0);
                }
                __builtin_amdgcn_s_setprio(0);
            }

            __builtin_amdgcn_s_barrier();
            __builtin_amdgcn_sched_barrier(0);
            if (kt + 1 < t1) issueV(kt + 1);
        }

        const int qrow = qbase + l15;
        if (mode == 0) {
            float inv = 1.0f / l_r;
            size_t base = (size_t)(b * S_ + qrow) * H_ + nh * HD_ + l4 * 4;
#pragma unroll
            for (int nc = 0; nc < 8; ++nc) {
                uint2 pk;
                pk.x = cvtpk(o[nc][0] * inv, o[nc][1] * inv);
                pk.y = cvtpk(o[nc][2] * inv, o[nc][3] * inv);
                *(uint2*)(Oa + base + nc * 16) = pk;
            }
        } else {
            const int base = bh * 16 + (qt - 16);
            const int c = (mode == 1) ? 0 : 1;
            float* mlrec = mlbuf + (size_t)(base * 2 + c) * 64 * 2;
            if (l4 == 0) {
                int row = w * 16 + l15;
                mlrec[row * 2 + 0] = m_r;
                mlrec[row * 2 + 1] = l_r;
            }
            if (mode == 1) {
                size_t ob = (size_t)(b * S_ + qrow) * H_ + nh * HD_ + l4 * 4;
#pragma unroll
                for (int nc = 0; nc < 8; ++nc) {
                    uint2 pk;
                    pk.x = cvtpk(o[nc][0], o[nc][1]);
                    pk.y = cvtpk(o[nc][2], o[nc][3]);
                    *(uint2*)(Oa + ob + nc * 16) = pk;
                }
            } else {
                size_t pb = ((size_t)base * 64 + w * 16 + l15) * 128 + l4 * 4;
#pragma unroll
                for (int nc = 0; nc < 8; ++nc) {
                    uint2 pk;
                    pk.x = cvtpk(o[nc][0], o[nc][1]);
                    pk.y = cvtpk(o[nc][2], o[nc][3]);
                    *(uint2*)(part1 + pb + nc * 16) = pk;
                }
            }
        }
    }
}

// ---------------- combine split-K partials ----------------
__global__ __launch_bounds__(256) void k_combine(
    const float* __restrict__ mlbuf, const unsigned short* __restrict__ part1,
    unsigned short* __restrict__ Oa) {
    int rec = blockIdx.x;                 // 0..511: bh*16 + (qt-16)
    int bh = rec >> 4, qt = 16 + (rec & 15);
    int b = bh >> 4, nh = bh & 15;
    int row = threadIdx.x >> 2;           // 0..63
    int dseg = (threadIdx.x & 3) * 32;
    const float* ml0 = mlbuf + (size_t)(rec * 2 + 0) * 128;
    const float* ml1 = mlbuf + (size_t)(rec * 2 + 1) * 128;
    float m0 = ml0[row * 2], l0 = ml0[row * 2 + 1];
    float m1 = ml1[row * 2], l1 = ml1[row * 2 + 1];
    float M = fmaxf(m0, m1);
    float a0 = exp2f(m0 - M), a1 = exp2f(m1 - M);
    float L = a0 * l0 + a1 * l1;
    float s0 = a0 / L, s1 = a1 / L;
    size_t ob = ((size_t)(b * S_) + qt * 64 + row) * H_ + nh * HD_ + dseg;
    const unsigned short* p1 = part1 + ((size_t)rec * 64 + row) * 128 + dseg;
#pragma unroll
    for (int i = 0; i < 4; ++i) {
        bf16x8 v0 = *(const bf16x8*)(Oa + ob + i * 8);
        bf16x8 v1 = *(const bf16x8*)(p1 + i * 8);
        bf16x8 oo;
#pragma unroll
        for (int e = 0; e < 8; ++e)
            oo[e] = (short)f2bf(bf2f((unsigned short)v0[e]) * s0 +
                                bf2f((unsigned short)v1[e]) * s1);
        *(bf16x8*)(Oa + ob + i * 8) = oo;
    }
}

// ---------------- launch ----------------
extern "C" void kernel_launch(void* const* d_in, const int* in_sizes, int n_in,
                              void* d_out, int out_size, void* d_ws, size_t ws_size,
                              hipStream_t stream) {
    const float* X  = (const float*)d_in[0];
    const float* Wq = (const float*)d_in[1];
    const float* bq = (const float*)d_in[2];
    const float* Wk = (const float*)d_in[3];
    const float* bk = (const float*)d_in[4];
    const float* Wv = (const float*)d_in[5];
    const float* bv = (const float*)d_in[6];
    const float* Wo = (const float*)d_in[7];
    const float* bo = (const float*)d_in[8];
    float* out = (float*)d_out;

    if (ws_size < 80000000) return;
    char* ws = (char*)d_ws;
    unsigned short* Xb    = (unsigned short*)(ws);              // 16.78 MB; reused as AOb
    unsigned short* WqkvT = (unsigned short*)(ws + 16777216);   // [3072][2048] 12.58 MB
    unsigned short* WoT   = (unsigned short*)(ws + 29360128);   // 8.39 MB
    unsigned short* QKV   = (unsigned short*)(ws + 37748736);   // [4096][3072] 25.17 MB (V region unused)
    unsigned short* VbT   = (unsigned short*)(ws + 62914560);   // 4.19 MB
    unsigned short* part1 = (unsigned short*)(ws + 67108864);   // 512*64*128 bf16 = 8.39 MB
    float*          mlbuf = (float*)(ws + 75497472);            // 1024*64*2 f32 = 512 KB
    float*          bqkv  = (float*)(ws + 76021760);            // 12 KB
    unsigned short* AOb   = Xb;                                 // Xb dead after QKV GEMM

    // fused prep: X cvt + Wqkv transpose + Wo transpose + bias concat (one dispatch)
    k_prep<<<dim3(18444), 256, 0, stream>>>(X, Wq, Wk, Wv, Wo, bq, bk, bv,
                                            Xb, WqkvT, WoT, bqkv);

    // fused QKV projection (V written directly as V^T): 256^2 8-phase, 16x12 grid
    k_gemm256<<<dim3(16, 12), 512, 0, stream>>>(Xb, WqkvT, bqkv, QKV, VbT, 4096, HQKV, 2048);

    k_flash<<<dim3(1024), 256, 0, stream>>>(QKV, VbT, AOb, part1, mlbuf);
    k_combine<<<dim3(512), 256, 0, stream>>>(mlbuf, part1, AOb);

    // O-projection: 256x128 8-phase, grid 16x16 = 256 blocks (full chip)
    k_gemm256x128<false><<<dim3(16, 16), 512, 0, stream>>>(AOb, WoT, bo, out, 4096, 2048, 2048);
}

// Round 17
// 210.820 us; speedup vs baseline: 1.1331x; 1.0125x over previous
//
#include <hip/hip_runtime.h>

// Problem constants
#define B_   2
#define S_   2048
#define H_   2048
#define NH_  16
#define G_   4
#define HD_  128
#define KV_  512
#define HQKV 3072   // fused Q|K|V output width

typedef __attribute__((ext_vector_type(8))) short bf16x8;
typedef __attribute__((ext_vector_type(4))) float f32x4;

__device__ __forceinline__ unsigned short f2bf(float f) {
    unsigned u = __float_as_uint(f);
    u += 0x7fff + ((u >> 16) & 1);   // RNE
    return (unsigned short)(u >> 16);
}
__device__ __forceinline__ float bf2f(unsigned short s) {
    return __uint_as_float(((unsigned)s) << 16);
}
// D.lo = bf16(a), D.hi = bf16(b)  (RNE)
__device__ __forceinline__ unsigned cvtpk(float a, float b) {
    unsigned r;
    asm volatile("v_cvt_pk_bf16_f32 %0, %1, %2" : "=v"(r) : "v"(a), "v"(b));
    return r;
}

#define GLDS16(gsrc, ldst)                                                            \
    __builtin_amdgcn_global_load_lds(                                                 \
        (const __attribute__((address_space(1))) void*)(gsrc),                        \
        (__attribute__((address_space(3))) void*)(ldst), 16, 0, 0)

// 1/sqrt(128) * log2(e): folded into Q columns of the QKV GEMM epilogue
#define SC2F (0.08838834764831843f * 1.4426950408889634f)

// ---------------- fused prep: cvt X | transpose Wq/Wk/Wv | transpose Wo | bias ----------------
// Block ranges: [0,8192) cvt X float4 (2,097,152 float4s = ALL of X);
// [8192,14336) Wqkv transpose (96x64); [14336,18432) Wo transpose (64x64);
// [18432,18444) bias concat.
__global__ __launch_bounds__(256) void k_prep(
    const float* __restrict__ X,  const float* __restrict__ Wq,
    const float* __restrict__ Wk, const float* __restrict__ Wv,
    const float* __restrict__ Wo, const float* __restrict__ bq,
    const float* __restrict__ bk, const float* __restrict__ bv,
    unsigned short* __restrict__ Xb, unsigned short* __restrict__ WqkvT,
    unsigned short* __restrict__ WoT, float* __restrict__ bqkv) {
    __shared__ float t[32][33];
    const int bid = blockIdx.x, tid = threadIdx.x;
    if (bid < 8192) {                       // X fp32 -> bf16 (2,097,152 float4s)
        int i = bid * 256 + tid;
        float4 v = ((const float4*)X)[i];
        ushort4 o;
        o.x = f2bf(v.x); o.y = f2bf(v.y); o.z = f2bf(v.z); o.w = f2bf(v.w);
        ((ushort4*)Xb)[i] = o;
        return;
    }
    const int tx = tid & 31, ty = tid >> 5;  // 32 x 8
    if (bid < 14336) {                      // Wq|Wk|Wv -> WqkvT [3072][2048]
        int idx = bid - 8192;
        int n0g = (idx % 96) * 32, h0 = (idx / 96) * 32;
        const float* src; int C, n0l;
        if (n0g < H_)            { src = Wq; C = H_;  n0l = n0g; }
        else if (n0g < H_ + KV_) { src = Wk; C = KV_; n0l = n0g - H_; }
        else                     { src = Wv; C = KV_; n0l = n0g - H_ - KV_; }
#pragma unroll
        for (int i = 0; i < 4; ++i)
            t[ty + i*8][tx] = src[(size_t)(h0 + ty + i*8) * C + n0l + tx];
        __syncthreads();
#pragma unroll
        for (int i = 0; i < 4; ++i)
            WqkvT[(size_t)(n0g + ty + i*8) * H_ + h0 + tx] = f2bf(t[tx][ty + i*8]);
        return;
    }
    if (bid < 18432) {                      // Wo -> WoT [2048][2048]
        int idx = bid - 14336;
        int c0 = (idx % 64) * 32, r0 = (idx / 64) * 32;
#pragma unroll
        for (int i = 0; i < 4; ++i)
            t[ty + i*8][tx] = Wo[(size_t)(r0 + ty + i*8) * H_ + c0 + tx];
        __syncthreads();
#pragma unroll
        for (int i = 0; i < 4; ++i)
            WoT[(size_t)(c0 + ty + i*8) * H_ + r0 + tx] = f2bf(t[tx][ty + i*8]);
        return;
    }
    int i = (bid - 18432) * 256 + tid;      // bias concat [3072]
    if (i < HQKV)
        bqkv[i] = (i < H_) ? bq[i] : (i < H_ + KV_ ? bk[i - H_] : bv[i - H_ - KV_]);
}

// ---------------- 256x256 8-phase bf16 GEMM (R14-validated) + fused V^T epilogue ----------------
__global__ __launch_bounds__(512, 2) void k_gemm256(
    const unsigned short* __restrict__ A, const unsigned short* __restrict__ Bt,
    const float* __restrict__ bias, unsigned short* __restrict__ Cout,
    unsigned short* __restrict__ VbT, int M, int N, int K) {
    __shared__ __align__(16) unsigned short As[2][256 * 64];
    __shared__ __align__(16) unsigned short Bs[2][256 * 64];
    const int tid = threadIdx.x, lane = tid & 63;
    const int w = tid >> 6;
    const int l15 = lane & 15, l4 = lane >> 4;
    const int wr = w >> 2, wc = w & 3;        // 2 x 4 wave grid
    const int m0 = blockIdx.x * 256, n0 = blockIdx.y * 256;
    f32x4 acc[8][4] = {};

    auto stageA = [&](int buf, int kt, int h) {
#pragma unroll
        for (int i = 0; i < 2; ++i) {
            int p = i * 512 + tid;
            int j = p >> 3;
            int row = h * 64 + (j >> 6) * 128 + (j & 63);
            int sc = p & 7;
            int c = sc ^ (row & 7);
            GLDS16(A + (size_t)(m0 + row) * K + kt * 64 + c * 8,
                   &As[buf][(row * 8 + sc) * 8]);
        }
    };
    auto stageB = [&](int buf, int kt, int h) {
#pragma unroll
        for (int i = 0; i < 2; ++i) {
            int p = i * 512 + tid;
            int j = p >> 3;
            int row = h * 32 + (j >> 5) * 64 + (j & 31);
            int sc = p & 7;
            int c = sc ^ (row & 7);
            GLDS16(Bt + (size_t)(n0 + row) * K + kt * 64 + c * 8,
                   &Bs[buf][(row * 8 + sc) * 8]);
        }
    };

    const int NT = K >> 6;
    stageB(0, 0, 0); stageA(0, 0, 0); stageB(0, 0, 1); stageA(0, 0, 1);
    stageB(1, 1, 0); stageA(1, 1, 0);

    bf16x8 bf[2][2];
    for (int t = 0; t < NT; ++t) {
        const int cur = t & 1, nxt = cur ^ 1;
        if (t == NT - 1) { asm volatile("s_waitcnt vmcnt(0)" ::: "memory"); }
        else             { asm volatile("s_waitcnt vmcnt(4)" ::: "memory"); }
        __builtin_amdgcn_s_barrier();
        __builtin_amdgcn_sched_barrier(0);

#pragma unroll
        for (int q = 0; q < 4; ++q) {
            const int nh = q >> 1, mh = q & 1;
            bf16x8 af[4][2];
#pragma unroll
            for (int mf2 = 0; mf2 < 4; ++mf2)
#pragma unroll
                for (int ks = 0; ks < 2; ++ks) {
                    int row = wr * 128 + (mh * 4 + mf2) * 16 + l15;
                    int ch = (ks * 4 + l4) ^ (row & 7);
                    af[mf2][ks] = *(const bf16x8*)(&As[cur][(row * 8 + ch) * 8]);
                }
            if (mh == 0) {
#pragma unroll
                for (int nf2 = 0; nf2 < 2; ++nf2)
#pragma unroll
                    for (int ks = 0; ks < 2; ++ks) {
                        int row = wc * 64 + (nh * 2 + nf2) * 16 + l15;
                        int ch = (ks * 4 + l4) ^ (row & 7);
                        bf[nf2][ks] = *(const bf16x8*)(&Bs[cur][(row * 8 + ch) * 8]);
                    }
            }
            if (q == 0)      { if (t + 1 < NT) stageB(nxt, t + 1, 1); }
            else if (q == 1) { if (t + 1 < NT) stageA(nxt, t + 1, 1); }
            else if (q == 2) { if (t + 2 < NT) stageB(cur, t + 2, 0); }
            else             { if (t + 2 < NT) stageA(cur, t + 2, 0); }

            __builtin_amdgcn_sched_barrier(0);
            __builtin_amdgcn_s_barrier();
            asm volatile("s_waitcnt lgkmcnt(0)" ::: "memory");
            __builtin_amdgcn_sched_barrier(0);
            __builtin_amdgcn_s_setprio(1);
#pragma unroll
            for (int mf2 = 0; mf2 < 4; ++mf2)
#pragma unroll
                for (int nf2 = 0; nf2 < 2; ++nf2)
#pragma unroll
                    for (int ks = 0; ks < 2; ++ks)
                        acc[mh * 4 + mf2][nh * 2 + nf2] = __builtin_amdgcn_mfma_f32_16x16x32_bf16(
                            af[mf2][ks], bf[nf2][ks], acc[mh * 4 + mf2][nh * 2 + nf2], 0, 0, 0);
            __builtin_amdgcn_s_setprio(0);
            __builtin_amdgcn_s_barrier();
        }
    }

#pragma unroll
    for (int mf = 0; mf < 8; ++mf) {
        int row = m0 + wr * 128 + mf * 16 + l4 * 4;
#pragma unroll
        for (int nf = 0; nf < 4; ++nf) {
            int col = n0 + wc * 64 + nf * 16 + l15;
            float bv = bias[col];
            if (col >= H_ + KV_) {
                // V region: write transposed only (flash consumes V^T)
                int vcol = col - (H_ + KV_);
#pragma unroll
                for (int r = 0; r < 4; ++r) {
                    int rr = row + r;
                    int b = rr >> 11, s = rr & 2047;
                    VbT[((size_t)b * KV_ + vcol) * S_ + s] = f2bf(acc[mf][nf][r] + bv);
                }
            } else {
                float sc = (col < H_) ? SC2F : 1.0f;
#pragma unroll
                for (int r = 0; r < 4; ++r) {
                    float v = (acc[mf][nf][r] + bv) * sc;
                    Cout[(size_t)(row + r) * N + col] = f2bf(v);
                }
            }
        }
    }
}

// ---------------- 256x128 8-phase bf16 GEMM (validated R11/R14, O-proj) ----------------
template <bool BF16OUT>
__global__ __launch_bounds__(512, 1) void k_gemm256x128(
    const unsigned short* __restrict__ A, const unsigned short* __restrict__ Bt,
    const float* __restrict__ bias, void* __restrict__ Cout, int M, int N, int K) {
    __shared__ __align__(16) unsigned short As[2][256 * 64];
    __shared__ __align__(16) unsigned short Bs[2][128 * 64];
    const int tid = threadIdx.x, lane = tid & 63;
    const int w = tid >> 6;
    const int l15 = lane & 15, l4 = lane >> 4;
    const int wr = w >> 2, wc = w & 3;        // 2 x 4 wave grid
    const int m0 = blockIdx.x * 256, n0 = blockIdx.y * 128;
    f32x4 acc[8][2] = {};

    auto stageA = [&](int buf, int kt, int h) {
#pragma unroll
        for (int i = 0; i < 2; ++i) {
            int p = i * 512 + tid;
            int j = p >> 3;
            int row = h * 64 + (j >> 6) * 128 + (j & 63);
            int sc = p & 7;
            int c = sc ^ (row & 7);
            GLDS16(A + (size_t)(m0 + row) * K + kt * 64 + c * 8,
                   &As[buf][(row * 8 + sc) * 8]);
        }
    };
    auto stageB = [&](int buf, int kt, int h) {
        int j = tid >> 3;                     // 0..63
        int row = h * 16 + (j >> 4) * 32 + (j & 15);   // stripe: bit4 == h
        int sc = tid & 7;
        int c = sc ^ (row & 7);
        GLDS16(Bt + (size_t)(n0 + row) * K + kt * 64 + c * 8,
               &Bs[buf][(row * 8 + sc) * 8]);
    };

    const int NT = K >> 6;
    stageB(0, 0, 0); stageA(0, 0, 0); stageB(0, 0, 1); stageA(0, 0, 1);
    stageB(1, 1, 0); stageA(1, 1, 0);

    bf16x8 bf[2];
    for (int t = 0; t < NT; ++t) {
        const int cur = t & 1, nxt = cur ^ 1;
        if (t == NT - 1) { asm volatile("s_waitcnt vmcnt(0)" ::: "memory"); }
        else             { asm volatile("s_waitcnt vmcnt(3)" ::: "memory"); }
        __builtin_amdgcn_s_barrier();
        __builtin_amdgcn_sched_barrier(0);

#pragma unroll
        for (int q = 0; q < 4; ++q) {
            const int nh = q >> 1, mh = q & 1;
            bf16x8 af[4][2];
#pragma unroll
            for (int mf2 = 0; mf2 < 4; ++mf2)
#pragma unroll
                for (int ks = 0; ks < 2; ++ks) {
                    int row = wr * 128 + (mh * 4 + mf2) * 16 + l15;
                    int ch = (ks * 4 + l4) ^ (row & 7);
                    af[mf2][ks] = *(const bf16x8*)(&As[cur][(row * 8 + ch) * 8]);
                }
            if (mh == 0) {
#pragma unroll
                for (int ks = 0; ks < 2; ++ks) {
                    int row = wc * 32 + nh * 16 + l15;
                    int ch = (ks * 4 + l4) ^ (row & 7);
                    bf[ks] = *(const bf16x8*)(&Bs[cur][(row * 8 + ch) * 8]);
                }
            }
            if (q == 0)      { if (t + 1 < NT) stageB(nxt, t + 1, 1); }
            else if (q == 1) { if (t + 1 < NT) stageA(nxt, t + 1, 1); }
            else if (q == 2) { if (t + 2 < NT) stageB(cur, t + 2, 0); }
            else             { if (t + 2 < NT) stageA(cur, t + 2, 0); }

            __builtin_amdgcn_sched_barrier(0);
            __builtin_amdgcn_s_barrier();
            asm volatile("s_waitcnt lgkmcnt(0)" ::: "memory");
            __builtin_amdgcn_sched_barrier(0);
            __builtin_amdgcn_s_setprio(1);
#pragma unroll
            for (int mf2 = 0; mf2 < 4; ++mf2)
#pragma unroll
                for (int ks = 0; ks < 2; ++ks)
                    acc[mh * 4 + mf2][nh] = __builtin_amdgcn_mfma_f32_16x16x32_bf16(
                        af[mf2][ks], bf[ks], acc[mh * 4 + mf2][nh], 0, 0, 0);
            __builtin_amdgcn_s_setprio(0);
            __builtin_amdgcn_s_barrier();
        }
    }

#pragma unroll
    for (int mf = 0; mf < 8; ++mf) {
        int row = m0 + wr * 128 + mf * 16 + l4 * 4;
#pragma unroll
        for (int nf = 0; nf < 2; ++nf) {
            int col = n0 + wc * 32 + nf * 16 + l15;
            float bv = bias[col];
#pragma unroll
            for (int r = 0; r < 4; ++r) {
                float v = acc[mf][nf][r] + bv;
                if (BF16OUT)
                    ((unsigned short*)Cout)[(size_t)(row + r) * N + col] = f2bf(v);
                else
                    ((float*)Cout)[(size_t)(row + r) * N + col] = v;
            }
        }
    }
}

// ---------------- causal GQA flash attention (R14-proven): QBLK=64, swapped-QK ----------------
// 1536 blocks, descending-work jobs, 4 heads pinned per XCD.
// __launch_bounds__(256,4): VGPR 64, zero spill ((256,5) spills: R13).
__global__ __launch_bounds__(256, 4) void k_flash(
    const unsigned short* __restrict__ QKV,  // [B*S][3072]  Q|K|V  (Q pre-scaled)
    const unsigned short* __restrict__ VT,   // [B][KV][S]
    unsigned short* __restrict__ Oa,         // [B*S][H]
    unsigned short* __restrict__ part1,      // [512][64][128] bf16 chunk1 partial O
    float* __restrict__ mlbuf) {             // [1024][64][2] f32 (m,l) per chunk
    __shared__ __align__(16) unsigned short Ks[64 * 128];    // K tile, chunk-swizzled
    __shared__ __align__(16) unsigned short Vs[128 * 64];    // V^T tile, chunk-swizzled
    const int tid = threadIdx.x, lane = tid & 63, w = tid >> 6;
    const int l15 = lane & 15, l4 = lane >> 4;
    const int bid = blockIdx.x;               // 0..1535
    const int xcd = bid & 7, idx = bid >> 3;  // 192 jobs per XCD
    const int bh = xcd * 4 + (idx & 3);       // 4 heads per XCD = one (b,g)
    const int jidx = idx >> 2;                // 0..47, descending work
    const int b = bh >> 4, nh = bh & 15, g = nh >> 2;

    int qt, t0, t1, mode;                     // mode: 0 full, 1 chunk0, 2 chunk1
    if (jidx < 16) { qt = 16 + jidx; t0 = 0; t1 = 16; mode = 1; }
    else {
        int k = jidx - 16, j = k >> 1;
        if ((k & 1) == 0) { qt = 31 - j; t0 = 16; t1 = qt + 1; mode = 2; }
        else              { qt = 15 - j; t0 = 0;  t1 = qt + 1; mode = 0; }
    }
    const int qbase = qt * 64 + w * 16;       // wave's 16 q-rows; lane's q = qbase + l15

    const unsigned short* kgbase = QKV + (size_t)b * S_ * HQKV + H_ + g * HD_;
    const unsigned short* vgbase = VT + ((size_t)b * KV_ + g * HD_) * S_;

    auto issueK = [&](int kt) {
        const int kv0 = kt * 64;
#pragma unroll
        for (int i = 0; i < 4; ++i) {
            int p = i * 256 + tid;
            int row = p >> 4, c = (p & 15) ^ (row & 15);
            GLDS16(kgbase + (size_t)(kv0 + row) * HQKV + c * 8, &Ks[(i * 256 + w * 64) * 8]);
        }
    };
    auto issueV = [&](int kt) {
        const int kv0 = kt * 64;
#pragma unroll
        for (int i = 0; i < 4; ++i) {
            int p = i * 256 + tid;
            int row = p >> 3, c = (p & 7) ^ (row & 7);
            GLDS16(vgbase + (size_t)row * S_ + kv0 + c * 8, &Vs[(i * 256 + w * 64) * 8]);
        }
    };

    bf16x8 qf[4];
#pragma unroll
    for (int kb = 0; kb < 4; ++kb)
        qf[kb] = *(const bf16x8*)(QKV + (size_t)(b * S_ + qbase + l15) * HQKV +
                                  nh * HD_ + kb * 32 + l4 * 8);

    f32x4 o[8] = {};                          // O^T: o[nc][r] = O[d=nc*16+l4*4+r][q=l15]
    float m_r = -1e30f, l_r = 0.f;

    const int src0 = l15 + 16 * ((2 * l4) & 3);
    const int src1 = l15 + 16 * ((2 * l4 + 1) & 3);
    const bool hsel = ((l4 >> 1) & 1) != 0;

    issueK(t0);
    issueV(t0);

    for (int kt = t0; kt < t1; ++kt) {
        const int kv0 = kt * 64;
        asm volatile("s_waitcnt vmcnt(4)" ::: "memory");
        __builtin_amdgcn_s_barrier();
        __builtin_amdgcn_sched_barrier(0);

        // S^T = K Q^T
        f32x4 s[4] = {};
#pragma unroll
        for (int kb = 0; kb < 4; ++kb) {
            bf16x8 kf[4];
#pragma unroll
            for (int n = 0; n < 4; ++n) {
                int row = n * 16 + l15;
                int sl = (kb * 4 + l4) ^ (row & 15);
                kf[n] = *(const bf16x8*)(&Ks[(row * 16 + sl) * 8]);
            }
            __builtin_amdgcn_s_setprio(1);
#pragma unroll
            for (int n = 0; n < 4; ++n)
                s[n] = __builtin_amdgcn_mfma_f32_16x16x32_bf16(kf[n], qf[kb], s[n], 0, 0, 0);
            __builtin_amdgcn_s_setprio(0);
        }
        if (kv0 + 63 > qbase) {
            const int qrow = qbase + l15;
#pragma unroll
            for (int n = 0; n < 4; ++n)
#pragma unroll
                for (int r = 0; r < 4; ++r) {
                    int kcol = kv0 + n * 16 + l4 * 4 + r;
                    if (kcol > qrow) s[n][r] = -1e30f;
                }
        }
        float pmax = s[0][0];
#pragma unroll
        for (int n = 0; n < 4; ++n)
#pragma unroll
            for (int r = 0; r < 4; ++r) pmax = fmaxf(pmax, s[n][r]);
        pmax = fmaxf(pmax, __shfl_xor(pmax, 16));
        pmax = fmaxf(pmax, __shfl_xor(pmax, 32));
        if (__any(pmax > m_r + 8.0f)) {
            float mn = fmaxf(m_r, pmax);
            float sf = exp2f(m_r - mn);
            m_r = mn;
            l_r *= sf;
#pragma unroll
            for (int nc = 0; nc < 8; ++nc) {
                f32x4 t = o[nc];
                t[0] *= sf; t[1] *= sf; t[2] *= sf; t[3] *= sf;
                o[nc] = t;
            }
        }
        float rsum = 0.f;
#pragma unroll
        for (int n = 0; n < 4; ++n)
#pragma unroll
            for (int r = 0; r < 4; ++r) {
                float p = exp2f(s[n][r] - m_r);
                s[n][r] = p;
                rsum += p;
            }
        rsum += __shfl_xor(rsum, 16);
        rsum += __shfl_xor(rsum, 32);
        l_r += rsum;

        unsigned plo[4], phi[4];
#pragma unroll
        for (int n = 0; n < 4; ++n) {
            plo[n] = cvtpk(s[n][0], s[n][1]);
            phi[n] = cvtpk(s[n][2], s[n][3]);
        }

        asm volatile("s_waitcnt vmcnt(0)" ::: "memory");
        __builtin_amdgcn_s_barrier();
        __builtin_amdgcn_sched_barrier(0);
        if (kt + 1 < t1) issueK(kt + 1);

#pragma unroll
        for (int kb = 0; kb < 2; ++kb) {
            const int n0i = 2 * kb, n1i = 2 * kb + 1;
            unsigned a0, a1, w0, w1, w2, w3;
            a0 = __shfl((int)plo[n0i], src0); a1 = __shfl((int)plo[n1i], src0); w0 = hsel ? a1 : a0;
            a0 = __shfl((int)phi[n0i], src0); a1 = __shfl((int)phi[n1i], src0); w1 = hsel ? a1 : a0;
            a0 = __shfl((int)plo[n0i], src1); a1 = __shfl((int)plo[n1i], src1); w2 = hsel ? a1 : a0;
            a0 = __shfl((int)phi[n0i], src1); a1 = __shfl((int)phi[n1i], src1); w3 = hsel ? a1 : a0;
            int4 pw = make_int4((int)w0, (int)w1, (int)w2, (int)w3);
            bf16x8 pf = *(bf16x8*)&pw;
            __builtin_amdgcn_s_setprio(1);
#pragma unroll
            for (int nc = 0; nc < 8; ++nc) {
                int row = nc * 16 + l15;
                int sl = (kb * 4 + l4) ^ (row & 7);
                bf16x8 vf = *(const bf16x8*)(&Vs[(row * 8 + sl) * 8]);
                o[nc] = __builtin_amdgcn_mfma_f32_16x16x32_bf16(vf, pf, o[nc], 0, 0, 0);
            }
            __builtin_amdgcn_s_setprio(0);
        }

        __builtin_amdgcn_s_barrier();
        __builtin_amdgcn_sched_barrier(0);
        if (kt + 1 < t1) issueV(kt + 1);
    }

    const int qrow = qbase + l15;
    if (mode == 0) {
        float inv = 1.0f / l_r;
        size_t base = (size_t)(b * S_ + qrow) * H_ + nh * HD_ + l4 * 4;
#pragma unroll
        for (int nc = 0; nc < 8; ++nc) {
            uint2 pk;
            pk.x = cvtpk(o[nc][0] * inv, o[nc][1] * inv);
            pk.y = cvtpk(o[nc][2] * inv, o[nc][3] * inv);
            *(uint2*)(Oa + base + nc * 16) = pk;
        }
    } else {
        const int base = bh * 16 + (qt - 16);
        const int c = (mode == 1) ? 0 : 1;
        float* mlrec = mlbuf + (size_t)(base * 2 + c) * 64 * 2;
        if (l4 == 0) {
            int row = w * 16 + l15;
            mlrec[row * 2 + 0] = m_r;
            mlrec[row * 2 + 1] = l_r;
        }
        if (mode == 1) {
            size_t ob = (size_t)(b * S_ + qrow) * H_ + nh * HD_ + l4 * 4;
#pragma unroll
            for (int nc = 0; nc < 8; ++nc) {
                uint2 pk;
                pk.x = cvtpk(o[nc][0], o[nc][1]);
                pk.y = cvtpk(o[nc][2], o[nc][3]);
                *(uint2*)(Oa + ob + nc * 16) = pk;
            }
        } else {
            size_t pb = ((size_t)base * 64 + w * 16 + l15) * 128 + l4 * 4;
#pragma unroll
            for (int nc = 0; nc < 8; ++nc) {
                uint2 pk;
                pk.x = cvtpk(o[nc][0], o[nc][1]);
                pk.y = cvtpk(o[nc][2], o[nc][3]);
                *(uint2*)(part1 + pb + nc * 16) = pk;
            }
        }
    }
}

// ---------------- combine split-K partials ----------------
__global__ __launch_bounds__(256) void k_combine(
    const float* __restrict__ mlbuf, const unsigned short* __restrict__ part1,
    unsigned short* __restrict__ Oa) {
    int rec = blockIdx.x;                 // 0..511: bh*16 + (qt-16)
    int bh = rec >> 4, qt = 16 + (rec & 15);
    int b = bh >> 4, nh = bh & 15;
    int row = threadIdx.x >> 2;           // 0..63
    int dseg = (threadIdx.x & 3) * 32;
    const float* ml0 = mlbuf + (size_t)(rec * 2 + 0) * 128;
    const float* ml1 = mlbuf + (size_t)(rec * 2 + 1) * 128;
    float m0 = ml0[row * 2], l0 = ml0[row * 2 + 1];
    float m1 = ml1[row * 2], l1 = ml1[row * 2 + 1];
    float M = fmaxf(m0, m1);
    float a0 = exp2f(m0 - M), a1 = exp2f(m1 - M);
    float L = a0 * l0 + a1 * l1;
    float s0 = a0 / L, s1 = a1 / L;
    size_t ob = ((size_t)(b * S_) + qt * 64 + row) * H_ + nh * HD_ + dseg;
    const unsigned short* p1 = part1 + ((size_t)rec * 64 + row) * 128 + dseg;
#pragma unroll
    for (int i = 0; i < 4; ++i) {
        bf16x8 v0 = *(const bf16x8*)(Oa + ob + i * 8);
        bf16x8 v1 = *(const bf16x8*)(p1 + i * 8);
        bf16x8 oo;
#pragma unroll
        for (int e = 0; e < 8; ++e)
            oo[e] = (short)f2bf(bf2f((unsigned short)v0[e]) * s0 +
                                bf2f((unsigned short)v1[e]) * s1);
        *(bf16x8*)(Oa + ob + i * 8) = oo;
    }
}

// ---------------- launch ----------------
extern "C" void kernel_launch(void* const* d_in, const int* in_sizes, int n_in,
                              void* d_out, int out_size, void* d_ws, size_t ws_size,
                              hipStream_t stream) {
    const float* X  = (const float*)d_in[0];
    const float* Wq = (const float*)d_in[1];
    const float* bq = (const float*)d_in[2];
    const float* Wk = (const float*)d_in[3];
    const float* bk = (const float*)d_in[4];
    const float* Wv = (const float*)d_in[5];
    const float* bv = (const float*)d_in[6];
    const float* Wo = (const float*)d_in[7];
    const float* bo = (const float*)d_in[8];
    float* out = (float*)d_out;

    if (ws_size < 80000000) return;
    char* ws = (char*)d_ws;
    unsigned short* Xb    = (unsigned short*)(ws);              // 16.78 MB; reused as AOb
    unsigned short* WqkvT = (unsigned short*)(ws + 16777216);   // [3072][2048] 12.58 MB
    unsigned short* WoT   = (unsigned short*)(ws + 29360128);   // 8.39 MB
    unsigned short* QKV   = (unsigned short*)(ws + 37748736);   // [4096][3072] 25.17 MB (V region unused)
    unsigned short* VbT   = (unsigned short*)(ws + 62914560);   // 4.19 MB
    unsigned short* part1 = (unsigned short*)(ws + 67108864);   // 512*64*128 bf16 = 8.39 MB
    float*          mlbuf = (float*)(ws + 75497472);            // 1024*64*2 f32 = 512 KB
    float*          bqkv  = (float*)(ws + 76021760);            // 12 KB
    unsigned short* AOb   = Xb;                                 // Xb dead after QKV GEMM

    // fused prep: X cvt + Wqkv transpose + Wo transpose + bias concat (one dispatch)
    k_prep<<<dim3(18444), 256, 0, stream>>>(X, Wq, Wk, Wv, Wo, bq, bk, bv,
                                            Xb, WqkvT, WoT, bqkv);

    // fused QKV projection (V written directly as V^T): 256^2 8-phase, 16x12 grid
    k_gemm256<<<dim3(16, 12), 512, 0, stream>>>(Xb, WqkvT, bqkv, QKV, VbT, 4096, HQKV, 2048);

    k_flash<<<dim3(1536), 256, 0, stream>>>(QKV, VbT, AOb, part1, mlbuf);
    k_combine<<<dim3(512), 256, 0, stream>>>(mlbuf, part1, AOb);

    // O-projection: 256x128 8-phase, grid 16x16 = 256 blocks (full chip)
    k_gemm256x128<false><<<dim3(16, 16), 512, 0, stream>>>(AOb, WoT, bo, out, 4096, 2048, 2048);
}